// Round 1
// baseline (800.513 us; speedup 1.0000x reference)
//
#include <hip/hip_runtime.h>
#include <math.h>

#define NROWS 8192

typedef __attribute__((ext_vector_type(8))) short short8;
typedef __attribute__((ext_vector_type(4))) float f32x4;

__device__ __forceinline__ unsigned short f2bf(float f) {
  union { float f; unsigned int u; } v; v.f = f;
  unsigned int u = v.u;
  unsigned int r = (u + 0x7fffu + ((u >> 16) & 1u)) >> 16;
  return (unsigned short)r;
}
__device__ __forceinline__ float bf2f(unsigned short h) {
  union { unsigned int u; float f; } v; v.u = ((unsigned int)h) << 16;
  return v.f;
}
__device__ __forceinline__ float sigmoidf_(float x) { return 1.0f / (1.0f + expf(-x)); }

// ---------------------------------------------------------------------------
// GEMM: C[R x M] = A[R x K] @ B[M x K]^T   (A,B bf16 row-major K-contiguous,
// C bf16). 128x128 tile, BK=64, 4 waves, mfma_f32_16x16x32_bf16,
// global_load_lds width-16 staging (m97 structure).
// ---------------------------------------------------------------------------
#define BM 128
#define BN 128
#define BK 64

__global__ __launch_bounds__(256) void gemm_bf16_bt(
    const unsigned short* __restrict__ A,
    const unsigned short* __restrict__ B,
    unsigned short* __restrict__ C,
    int K, int lda, int ldb, int ldc)
{
  __shared__ unsigned short lA[BM * BK];
  __shared__ unsigned short lB[BN * BK];
  const int tid  = threadIdx.x;
  const int wave = tid >> 6;
  const int lane = tid & 63;
  const int brow = blockIdx.y * BM;
  const int bcol = blockIdx.x * BN;
  const int wr = (wave >> 1) * 64;   // wave row offset in tile
  const int wc = (wave & 1) * 64;    // wave col offset in tile
  const int lr = lane & 15;          // fragment row/col
  const int kg = (lane >> 4) * 8;    // fragment k-offset
  const int srow  = wave * 32;       // staging rows base for this wave
  const int glrow = lane >> 3;       // 0..7
  const int glcol = (lane & 7) * 8;  // element offset within row

  f32x4 acc[4][4];
#pragma unroll
  for (int m = 0; m < 4; ++m)
#pragma unroll
    for (int n = 0; n < 4; ++n)
      acc[m][n] = (f32x4){0.f, 0.f, 0.f, 0.f};

  for (int k0 = 0; k0 < K; k0 += BK) {
#pragma unroll
    for (int i = 0; i < 4; ++i) {
      const int r = srow + i * 8;
      const unsigned short* ga = A + (size_t)(brow + r + glrow) * lda + k0 + glcol;
      __builtin_amdgcn_global_load_lds(
          (const __attribute__((address_space(1))) void*)ga,
          (__attribute__((address_space(3))) void*)&lA[r * BK], 16, 0, 0);
      const unsigned short* gb = B + (size_t)(bcol + r + glrow) * ldb + k0 + glcol;
      __builtin_amdgcn_global_load_lds(
          (const __attribute__((address_space(1))) void*)gb,
          (__attribute__((address_space(3))) void*)&lB[r * BK], 16, 0, 0);
    }
    __syncthreads();
#pragma unroll
    for (int kk = 0; kk < BK; kk += 32) {
      short8 af[4], bfr[4];
#pragma unroll
      for (int m = 0; m < 4; ++m)
        af[m] = *(const short8*)&lA[(wr + m * 16 + lr) * BK + kk + kg];
#pragma unroll
      for (int n = 0; n < 4; ++n)
        bfr[n] = *(const short8*)&lB[(wc + n * 16 + lr) * BK + kk + kg];
#pragma unroll
      for (int m = 0; m < 4; ++m)
#pragma unroll
        for (int n = 0; n < 4; ++n)
          acc[m][n] = __builtin_amdgcn_mfma_f32_16x16x32_bf16(af[m], bfr[n], acc[m][n], 0, 0, 0);
    }
    __syncthreads();
  }

  const int crow0 = brow + wr + (lane >> 4) * 4;
#pragma unroll
  for (int m = 0; m < 4; ++m) {
#pragma unroll
    for (int n = 0; n < 4; ++n) {
      const int col = bcol + wc + n * 16 + lr;
#pragma unroll
      for (int j = 0; j < 4; ++j)
        C[(size_t)(crow0 + m * 16 + j) * ldc + col] = f2bf(acc[m][n][j]);
    }
  }
}

// ---------------------------------------------------------------------------
// Packing kernels (fp32 -> bf16), vectorized x4
// ---------------------------------------------------------------------------
__global__ void cast_bf16_kernel(unsigned short* __restrict__ dst,
                                 const float* __restrict__ src, size_t n4)
{
  size_t idx = (size_t)blockIdx.x * blockDim.x + threadIdx.x;
  if (idx >= n4) return;
  float4 v = ((const float4*)src)[idx];
  ushort4 o;
  o.x = f2bf(v.x); o.y = f2bf(v.y); o.z = f2bf(v.z); o.w = f2bf(v.w);
  ((ushort4*)dst)[idx] = o;
}

// dst[n][i*1024+j] = bf16(s_i[n][j]); lw = log2(row width of dst)
__global__ void pack_cat_kernel(unsigned short* __restrict__ dst,
                                const float* __restrict__ s0, const float* __restrict__ s1,
                                const float* __restrict__ s2, const float* __restrict__ s3,
                                int lw)
{
  size_t idx = ((size_t)blockIdx.x * blockDim.x + threadIdx.x) * 4;
  size_t n = idx >> lw;
  int rem = (int)(idx & (((size_t)1 << lw) - 1));
  int i = rem >> 10, j = rem & 1023;
  const float* s = (i == 0) ? s0 : (i == 1) ? s1 : (i == 2) ? s2 : s3;
  float4 v = *(const float4*)&s[(n << 10) + j];
  ushort4 o;
  o.x = f2bf(v.x); o.y = f2bf(v.y); o.z = f2bf(v.z); o.w = f2bf(v.w);
  *(ushort4*)&dst[idx] = o;
}

// W4[4096][4096]: rows [0,1024)=W_i, [1024,2048)=W_fl, [2048,3072)=W_fr,
// [3072,4096)=W_g (K<2048) else 0
__global__ void pack_w4_kernel(unsigned short* __restrict__ dst,
                               const float* __restrict__ Wi, const float* __restrict__ Wfl,
                               const float* __restrict__ Wfr, const float* __restrict__ Wg)
{
  size_t idx = ((size_t)blockIdx.x * blockDim.x + threadIdx.x) * 4;
  int m = (int)(idx >> 12);
  int k = (int)(idx & 4095);
  float4 v;
  if (m < 3072) {
    const float* W = (m < 1024) ? Wi : (m < 2048) ? Wfl : Wfr;
    v = *(const float4*)&W[(size_t)(m & 1023) * 4096 + k];
  } else {
    int g = m - 3072;
    if (k < 2048) v = *(const float4*)&Wg[(size_t)g * 2048 + k];
    else          v = make_float4(0.f, 0.f, 0.f, 0.f);
  }
  ushort4 o;
  o.x = f2bf(v.x); o.y = f2bf(v.y); o.z = f2bf(v.z); o.w = f2bf(v.w);
  *(ushort4*)&dst[idx] = o;
}

// ---------------------------------------------------------------------------
// Elementwise epilogues
// ---------------------------------------------------------------------------
__global__ void ew1_kernel(const unsigned short* __restrict__ zp, const float* __restrict__ bz,
                           const float* __restrict__ xl, const float* __restrict__ xr,
                           float* __restrict__ out_x, unsigned short* __restrict__ A2)
{
  size_t idx = (size_t)blockIdx.x * blockDim.x + threadIdx.x;
  int j = (int)(idx & 1023);
  float z = sigmoidf_(bf2f(zp[idx]) + bz[j]);
  float xt = z * xl[idx] + (1.f - z) * xr[idx];
  out_x[idx] = xt;
  A2[idx] = f2bf(xt);
}

__global__ void ew2_kernel(const unsigned short* __restrict__ pre4, const unsigned short* __restrict__ xin,
                           const float* __restrict__ b_i, const float* __restrict__ b_fl,
                           const float* __restrict__ b_fr, const float* __restrict__ b_g,
                           const float* __restrict__ cl, const float* __restrict__ cr,
                           float* __restrict__ out_c, unsigned short* __restrict__ A3)
{
  size_t idx = (size_t)blockIdx.x * blockDim.x + threadIdx.x;
  int j = (int)(idx & 1023);
  size_t n = idx >> 10;
  size_t r4 = n << 12;
  float xi = bf2f(xin[r4 + j]);
  float xf = bf2f(xin[r4 + 1024 + j]);
  float xg = bf2f(xin[r4 + 3072 + j]);
  float it = sigmoidf_(bf2f(pre4[r4 + j]) + b_i[j] + xi);
  float fl = sigmoidf_(bf2f(pre4[r4 + 1024 + j]) + b_fl[j] + xf);
  float fr = sigmoidf_(bf2f(pre4[r4 + 2048 + j]) + b_fr[j] + xf);
  float g  = tanhf(bf2f(pre4[r4 + 3072 + j]) + b_g[j] + xg);
  float c = fl * cl[idx] + fr * cr[idx] + it * g;
  out_c[idx] = c;
  A3[r4 + 2048 + j] = f2bf(c);   // c_t replaces c_l columns for the o-GEMM
}

__global__ void ew3_kernel(const unsigned short* __restrict__ opre, const float* __restrict__ b_o,
                           const unsigned short* __restrict__ xin, const float* __restrict__ out_c,
                           float* __restrict__ out_h)
{
  size_t idx = (size_t)blockIdx.x * blockDim.x + threadIdx.x;
  int j = (int)(idx & 1023);
  size_t n = idx >> 10;
  float xo = bf2f(xin[(n << 12) + 2048 + j]);
  float o = sigmoidf_(bf2f(opre[idx]) + b_o[j] + xo);
  out_h[idx] = o * tanhf(out_c[idx]);
}

// ---------------------------------------------------------------------------
extern "C" void kernel_launch(void* const* d_in, const int* in_sizes, int n_in,
                              void* d_out, int out_size, void* d_ws, size_t ws_size,
                              hipStream_t stream)
{
  const float* x_l  = (const float*)d_in[0];
  const float* h_l  = (const float*)d_in[1];
  const float* c_l  = (const float*)d_in[2];
  const float* x_r  = (const float*)d_in[3];
  const float* h_r  = (const float*)d_in[4];
  const float* c_r  = (const float*)d_in[5];
  const float* W_i  = (const float*)d_in[6];
  const float* b_i  = (const float*)d_in[7];
  const float* W_fl = (const float*)d_in[8];
  const float* b_fl = (const float*)d_in[9];
  const float* W_fr = (const float*)d_in[10];
  const float* b_fr = (const float*)d_in[11];
  const float* W_xin= (const float*)d_in[12];
  const float* W_o  = (const float*)d_in[13];
  const float* b_o  = (const float*)d_in[14];
  const float* W_z  = (const float*)d_in[15];
  const float* b_z  = (const float*)d_in[16];
  const float* W_g  = (const float*)d_in[17];
  const float* b_g  = (const float*)d_in[18];

  float* out_x = (float*)d_out;
  float* out_h = out_x + (size_t)NROWS * 1024;
  float* out_c = out_x + 2 * (size_t)NROWS * 1024;

  char* ws = (char*)d_ws;
  // layout (bytes):
  //   [0, 64M)      xin bf16 (N x 4096)     | A1 bf16 (N x 2048) overlapped
  //   [64M, 128M)   A3  bf16 (N x 4096)     | A2 bf16 (N x 1024) overlapped
  //   [128M, 192M)  pre4 bf16 (N x 4096)    | z_pre / o_pre bf16 overlapped
  //   [192M, 224M)  Wbuf bf16 (4096 x 4096 max)
  unsigned short* xin  = (unsigned short*)ws;
  unsigned short* A1   = (unsigned short*)ws;
  unsigned short* A3   = (unsigned short*)(ws + 67108864);
  unsigned short* A2   = A3;
  unsigned short* pre4 = (unsigned short*)(ws + 134217728);
  unsigned short* zpre = pre4;
  unsigned short* opre = pre4;
  unsigned short* Wb   = (unsigned short*)(ws + 201326592);

  const dim3 blk(256);
  const size_t NE = (size_t)NROWS * 1024;   // 8388608 elements per [N,1024] tensor

  // ---- stage A: z gate -> x_t ----
  cast_bf16_kernel<<<dim3((1024u * 2048u / 4) / 256), blk, 0, stream>>>(Wb, W_z, 1024 * 2048 / 4);
  pack_cat_kernel<<<dim3((unsigned)(NE * 2 / 4 / 256)), blk, 0, stream>>>(A1, x_l, x_r, x_l, x_l, 11);
  gemm_bf16_bt<<<dim3(1024 / BN, NROWS / BM), blk, 0, stream>>>(A1, Wb, zpre, 2048, 2048, 2048, 1024);
  ew1_kernel<<<dim3((unsigned)(NE / 256)), blk, 0, stream>>>(zpre, b_z, x_l, x_r, out_x, A2);

  // ---- stage B: x_in = x_t @ W_xin^T ----
  cast_bf16_kernel<<<dim3((4096u * 1024u / 4) / 256), blk, 0, stream>>>(Wb, W_xin, 4096 * 1024 / 4);
  gemm_bf16_bt<<<dim3(4096 / BN, NROWS / BM), blk, 0, stream>>>(A2, Wb, xin, 1024, 1024, 1024, 4096);

  // ---- stage C: fused i/fl/fr/g GEMM -> c_t ----
  pack_w4_kernel<<<dim3((4096u * 4096u / 4) / 256), blk, 0, stream>>>(Wb, W_i, W_fl, W_fr, W_g);
  pack_cat_kernel<<<dim3((unsigned)(NE * 4 / 4 / 256)), blk, 0, stream>>>(A3, h_l, h_r, c_l, c_r, 12);
  gemm_bf16_bt<<<dim3(4096 / BN, NROWS / BM), blk, 0, stream>>>(A3, Wb, pre4, 4096, 4096, 4096, 4096);
  ew2_kernel<<<dim3((unsigned)(NE / 256)), blk, 0, stream>>>(pre4, xin, b_i, b_fl, b_fr, b_g,
                                                             c_l, c_r, out_c, A3);

  // ---- stage D: o gate -> h_t ----
  cast_bf16_kernel<<<dim3((1024u * 3072u / 4) / 256), blk, 0, stream>>>(Wb, W_o, 1024 * 3072 / 4);
  gemm_bf16_bt<<<dim3(1024 / BN, NROWS / BM), blk, 0, stream>>>(A3, Wb, opre, 3072, 4096, 3072, 1024);
  ew3_kernel<<<dim3((unsigned)(NE / 256)), blk, 0, stream>>>(opre, b_o, xin, out_c, out_h);
}

// Round 2
// 605.695 us; speedup vs baseline: 1.3216x; 1.3216x over previous
//
#include <hip/hip_runtime.h>
#include <math.h>

#define NROWS 8192

typedef __attribute__((ext_vector_type(8))) short short8;
typedef __attribute__((ext_vector_type(4))) float f32x4;

__device__ __forceinline__ unsigned short f2bf(float f) {
  union { float f; unsigned int u; } v; v.f = f;
  unsigned int u = v.u;
  unsigned int r = (u + 0x7fffu + ((u >> 16) & 1u)) >> 16;
  return (unsigned short)r;
}
__device__ __forceinline__ float bf2f(unsigned short h) {
  union { unsigned int u; float f; } v; v.u = ((unsigned int)h) << 16;
  return v.f;
}
__device__ __forceinline__ float sigmoidf_(float x) { return 1.0f / (1.0f + expf(-x)); }

// ---------------------------------------------------------------------------
// 256x256 8-phase GEMM (m201 template, plain HIP):
//   C[R x M] = A[R x K] @ B[M x K]^T, A/B bf16 K-contiguous, C bf16.
//   8 waves (2Mx4N), BK=64, 2 K-tiles per iteration, 128 KiB LDS dbuf,
//   counted vmcnt(4) at phases 4/8, setprio around MFMA, XOR-16B-unit swizzle
//   (pre-swizzled global source + swizzled ds_read; linear global_load_lds dest).
// ---------------------------------------------------------------------------
#define FENCE __builtin_amdgcn_sched_barrier(0)
#define BAR   __builtin_amdgcn_s_barrier()
#define WAIT_LGKM do { asm volatile("s_waitcnt lgkmcnt(0)" ::: "memory"); } while (0)
#define WAIT_VM4  do { asm volatile("s_waitcnt vmcnt(4)" ::: "memory"); } while (0)
#define WAIT_VM0  do { asm volatile("s_waitcnt vmcnt(0)" ::: "memory"); } while (0)

// LDS layout (ushorts): [(buf*2 + mat)*2 + half] * 8192, half = [128][64] linear
#define LA(buf, h) (((buf) * 4 + (h)) * 8192)
#define LB(buf, h) (((buf) * 4 + 2 + (h)) * 8192)

__global__ __launch_bounds__(512) void gemm256(
    const unsigned short* __restrict__ A,
    const unsigned short* __restrict__ B,
    unsigned short* __restrict__ C,
    int K, int lda, int ldb, int ldc, int nbx)
{
  __shared__ unsigned short lds[65536];  // 128 KiB
  const int tid  = threadIdx.x;
  const int wave = tid >> 6;
  const int lane = tid & 63;
  const int wm = wave >> 2;          // 0..1  (M half of tile, 128 rows)
  const int wn = wave & 3;           // 0..3  (N quarter, 64 cols)
  const int lr = lane & 15;
  const int kq = lane >> 4;          // 0..3
  const int rsub = lane >> 3;        // staging row-in-chunk 0..7
  const int usw  = (lane & 7) ^ rsub; // pre-swizzled source unit

  // XCD-aware bijective swizzle (grid % 8 == 0 for all call sites)
  const int nwg = (int)gridDim.x;
  const int bid = (int)blockIdx.x;
  const int swz = (bid & 7) * (nwg >> 3) + (bid >> 3);
  const int brow = (swz / nbx) * 256;
  const int bcol = (swz % nbx) * 256;

  const int nkt = K >> 6;            // 64-wide K-tiles
  const int niter = K >> 7;          // 2 K-tiles per iteration

  f32x4 acc[8][4];
#pragma unroll
  for (int m = 0; m < 8; ++m)
#pragma unroll
    for (int n = 0; n < 4; ++n)
      acc[m][n] = (f32x4){0.f, 0.f, 0.f, 0.f};

  // stage one half-tile unit (128 rows x 64 cols bf16 = 16KB = 2 loads/thread)
  auto STAGE = [&](const unsigned short* src, int ld, int rowbase, int base_us, int kt) {
    const int k0 = (kt < nkt) ? (kt << 6) : 0;
#pragma unroll
    for (int j = 0; j < 2; ++j) {
      const int chunk = wave * 2 + j;
      const unsigned short* g = src + (size_t)(rowbase + chunk * 8 + rsub) * ld + k0 + usw * 8;
      __builtin_amdgcn_global_load_lds(
          (const __attribute__((address_space(1))) void*)g,
          (__attribute__((address_space(3))) void*)&lds[base_us + chunk * 512], 16, 0, 0);
    }
  };

  short8 aM[8], aM2[8], bN[4];

  auto LDA_ = [&](int buf, int mh, short8* d) {
#pragma unroll
    for (int m = 0; m < 4; ++m)
#pragma unroll
      for (int kk = 0; kk < 2; ++kk) {
        const int r = mh * 64 + m * 16 + lr;
        const int u = (kk * 4 + kq) ^ (lr & 7);
        d[m * 2 + kk] = *(const short8*)&lds[LA(buf, wm) + r * 64 + u * 8];
      }
  };
  auto LDB_ = [&](int buf, int nh, short8* d) {
#pragma unroll
    for (int n = 0; n < 2; ++n)
#pragma unroll
      for (int kk = 0; kk < 2; ++kk) {
        const int r = (wn & 1) * 64 + nh * 32 + n * 16 + lr;
        const int u = (kk * 4 + kq) ^ (lr & 7);
        d[n * 2 + kk] = *(const short8*)&lds[LB(buf, wn >> 1) + r * 64 + u * 8];
      }
  };
  auto MM_ = [&](int mh, int nh, short8* a, short8* b) {
#pragma unroll
    for (int m = 0; m < 4; ++m)
#pragma unroll
      for (int n = 0; n < 2; ++n)
#pragma unroll
        for (int kk = 0; kk < 2; ++kk)
          acc[mh * 4 + m][nh * 2 + n] = __builtin_amdgcn_mfma_f32_16x16x32_bf16(
              a[m * 2 + kk], b[n * 2 + kk], acc[mh * 4 + m][nh * 2 + n], 0, 0, 0);
  };

  // ---- prologue: buf0 <- ktile 0 (4 units), buf1.A <- ktile 1 (2 units) ----
  STAGE(A, lda, brow,       LA(0, 0), 0);
  STAGE(A, lda, brow + 128, LA(0, 1), 0);
  STAGE(B, ldb, bcol,       LB(0, 0), 0);
  STAGE(B, ldb, bcol + 128, LB(0, 1), 0);
  STAGE(A, lda, brow,       LA(1, 0), 1);
  STAGE(A, lda, brow + 128, LA(1, 1), 1);
  WAIT_VM4; FENCE; BAR;

  for (int i = 0; i < niter; ++i) {
    const int t1 = 2 * i + 1, t2 = 2 * i + 2, t3 = 2 * i + 3;
    // P1: Q(M0,N0) of buf0 | stage buf1.Bh0 <- t1
    LDA_(0, 0, aM); LDB_(0, 0, bN);
    STAGE(B, ldb, bcol,       LB(1, 0), t1);
    FENCE; BAR; WAIT_LGKM; FENCE;
    __builtin_amdgcn_s_setprio(1); MM_(0, 0, aM, bN); __builtin_amdgcn_s_setprio(0);
    FENCE; BAR;
    // P2: Q(M1,N0) | stage buf1.Bh1 <- t1
    LDA_(0, 1, aM2);
    STAGE(B, ldb, bcol + 128, LB(1, 1), t1);
    FENCE; BAR; WAIT_LGKM; FENCE;
    __builtin_amdgcn_s_setprio(1); MM_(1, 0, aM2, bN); __builtin_amdgcn_s_setprio(0);
    FENCE; BAR;
    // P3: Q(M0,N1) | stage buf0.Ah0 <- t2   (buf0.A last read at P2)
    LDB_(0, 1, bN);
    STAGE(A, lda, brow,       LA(0, 0), t2);
    FENCE; BAR; WAIT_LGKM; FENCE;
    __builtin_amdgcn_s_setprio(1); MM_(0, 1, aM, bN); __builtin_amdgcn_s_setprio(0);
    FENCE; BAR;
    // P4: Q(M1,N1) | stage buf0.Ah1 <- t2 | vmcnt(4): t1's 4 units landed
    STAGE(A, lda, brow + 128, LA(0, 1), t2);
    FENCE; BAR; WAIT_LGKM; FENCE;
    __builtin_amdgcn_s_setprio(1); MM_(1, 1, aM2, bN); __builtin_amdgcn_s_setprio(0);
    WAIT_VM4; FENCE; BAR;
    // P5: Q(M0,N0) of buf1 | stage buf0.Bh0 <- t2   (buf0.B last read at P3)
    LDA_(1, 0, aM); LDB_(1, 0, bN);
    STAGE(B, ldb, bcol,       LB(0, 0), t2);
    FENCE; BAR; WAIT_LGKM; FENCE;
    __builtin_amdgcn_s_setprio(1); MM_(0, 0, aM, bN); __builtin_amdgcn_s_setprio(0);
    FENCE; BAR;
    // P6: Q(M1,N0) | stage buf0.Bh1 <- t2
    LDA_(1, 1, aM2);
    STAGE(B, ldb, bcol + 128, LB(0, 1), t2);
    FENCE; BAR; WAIT_LGKM; FENCE;
    __builtin_amdgcn_s_setprio(1); MM_(1, 0, aM2, bN); __builtin_amdgcn_s_setprio(0);
    FENCE; BAR;
    // P7: Q(M0,N1) | stage buf1.Ah0 <- t3   (buf1.A last read at P6)
    LDB_(1, 1, bN);
    STAGE(A, lda, brow,       LA(1, 0), t3);
    FENCE; BAR; WAIT_LGKM; FENCE;
    __builtin_amdgcn_s_setprio(1); MM_(0, 1, aM, bN); __builtin_amdgcn_s_setprio(0);
    FENCE; BAR;
    // P8: Q(M1,N1) | stage buf1.Ah1 <- t3 | vmcnt(4): t2's 4 units landed
    STAGE(A, lda, brow + 128, LA(1, 1), t3);
    FENCE; BAR; WAIT_LGKM; FENCE;
    __builtin_amdgcn_s_setprio(1); MM_(1, 1, aM2, bN); __builtin_amdgcn_s_setprio(0);
    WAIT_VM4; FENCE; BAR;
  }

  WAIT_VM0;  // drain garbage prefetches before workgroup retires

  // ---- epilogue: acc[mi][ni] covers rows wm*128 + mi*16, cols wn*64 + ni*16 ----
  const int crow0 = brow + wm * 128 + kq * 4;
  const int ccol0 = bcol + wn * 64 + lr;
#pragma unroll
  for (int mi = 0; mi < 8; ++mi)
#pragma unroll
    for (int ni = 0; ni < 4; ++ni)
#pragma unroll
      for (int j = 0; j < 4; ++j)
        C[(size_t)(crow0 + mi * 16 + j) * ldc + ccol0 + ni * 16] = f2bf(acc[mi][ni][j]);
}

// ---------------------------------------------------------------------------
// Packing kernels (fp32 -> bf16), vectorized x4
// ---------------------------------------------------------------------------
__global__ void cast_bf16_kernel(unsigned short* __restrict__ dst,
                                 const float* __restrict__ src, size_t n4)
{
  size_t idx = (size_t)blockIdx.x * blockDim.x + threadIdx.x;
  if (idx >= n4) return;
  float4 v = ((const float4*)src)[idx];
  ushort4 o;
  o.x = f2bf(v.x); o.y = f2bf(v.y); o.z = f2bf(v.z); o.w = f2bf(v.w);
  ((ushort4*)dst)[idx] = o;
}

__global__ void pack_cat_kernel(unsigned short* __restrict__ dst,
                                const float* __restrict__ s0, const float* __restrict__ s1,
                                const float* __restrict__ s2, const float* __restrict__ s3,
                                int lw)
{
  size_t idx = ((size_t)blockIdx.x * blockDim.x + threadIdx.x) * 4;
  size_t n = idx >> lw;
  int rem = (int)(idx & (((size_t)1 << lw) - 1));
  int i = rem >> 10, j = rem & 1023;
  const float* s = (i == 0) ? s0 : (i == 1) ? s1 : (i == 2) ? s2 : s3;
  float4 v = *(const float4*)&s[(n << 10) + j];
  ushort4 o;
  o.x = f2bf(v.x); o.y = f2bf(v.y); o.z = f2bf(v.z); o.w = f2bf(v.w);
  *(ushort4*)&dst[idx] = o;
}

__global__ void pack_w4_kernel(unsigned short* __restrict__ dst,
                               const float* __restrict__ Wi, const float* __restrict__ Wfl,
                               const float* __restrict__ Wfr, const float* __restrict__ Wg)
{
  size_t idx = ((size_t)blockIdx.x * blockDim.x + threadIdx.x) * 4;
  int m = (int)(idx >> 12);
  int k = (int)(idx & 4095);
  float4 v;
  if (m < 3072) {
    const float* W = (m < 1024) ? Wi : (m < 2048) ? Wfl : Wfr;
    v = *(const float4*)&W[(size_t)(m & 1023) * 4096 + k];
  } else {
    int g = m - 3072;
    if (k < 2048) v = *(const float4*)&Wg[(size_t)g * 2048 + k];
    else          v = make_float4(0.f, 0.f, 0.f, 0.f);
  }
  ushort4 o;
  o.x = f2bf(v.x); o.y = f2bf(v.y); o.z = f2bf(v.z); o.w = f2bf(v.w);
  *(ushort4*)&dst[idx] = o;
}

// ---------------------------------------------------------------------------
// Elementwise epilogues
// ---------------------------------------------------------------------------
__global__ void ew1_kernel(const unsigned short* __restrict__ zp, const float* __restrict__ bz,
                           const float* __restrict__ xl, const float* __restrict__ xr,
                           float* __restrict__ out_x, unsigned short* __restrict__ A2)
{
  size_t idx = (size_t)blockIdx.x * blockDim.x + threadIdx.x;
  int j = (int)(idx & 1023);
  float z = sigmoidf_(bf2f(zp[idx]) + bz[j]);
  float xt = z * xl[idx] + (1.f - z) * xr[idx];
  out_x[idx] = xt;
  A2[idx] = f2bf(xt);
}

__global__ void ew2_kernel(const unsigned short* __restrict__ pre4, const unsigned short* __restrict__ xin,
                           const float* __restrict__ b_i, const float* __restrict__ b_fl,
                           const float* __restrict__ b_fr, const float* __restrict__ b_g,
                           const float* __restrict__ cl, const float* __restrict__ cr,
                           float* __restrict__ out_c, unsigned short* __restrict__ A3)
{
  size_t idx = (size_t)blockIdx.x * blockDim.x + threadIdx.x;
  int j = (int)(idx & 1023);
  size_t n = idx >> 10;
  size_t r4 = n << 12;
  float xi = bf2f(xin[r4 + j]);
  float xf = bf2f(xin[r4 + 1024 + j]);
  float xg = bf2f(xin[r4 + 3072 + j]);
  float it = sigmoidf_(bf2f(pre4[r4 + j]) + b_i[j] + xi);
  float fl = sigmoidf_(bf2f(pre4[r4 + 1024 + j]) + b_fl[j] + xf);
  float fr = sigmoidf_(bf2f(pre4[r4 + 2048 + j]) + b_fr[j] + xf);
  float g  = tanhf(bf2f(pre4[r4 + 3072 + j]) + b_g[j] + xg);
  float c = fl * cl[idx] + fr * cr[idx] + it * g;
  out_c[idx] = c;
  A3[r4 + 2048 + j] = f2bf(c);   // c_t replaces c_l columns for the o-GEMM
}

__global__ void ew3_kernel(const unsigned short* __restrict__ opre, const float* __restrict__ b_o,
                           const unsigned short* __restrict__ xin, const float* __restrict__ out_c,
                           float* __restrict__ out_h)
{
  size_t idx = (size_t)blockIdx.x * blockDim.x + threadIdx.x;
  int j = (int)(idx & 1023);
  size_t n = idx >> 10;
  float xo = bf2f(xin[(n << 12) + 2048 + j]);
  float o = sigmoidf_(bf2f(opre[idx]) + b_o[j] + xo);
  out_h[idx] = o * tanhf(out_c[idx]);
}

// ---------------------------------------------------------------------------
extern "C" void kernel_launch(void* const* d_in, const int* in_sizes, int n_in,
                              void* d_out, int out_size, void* d_ws, size_t ws_size,
                              hipStream_t stream)
{
  const float* x_l  = (const float*)d_in[0];
  const float* h_l  = (const float*)d_in[1];
  const float* c_l  = (const float*)d_in[2];
  const float* x_r  = (const float*)d_in[3];
  const float* h_r  = (const float*)d_in[4];
  const float* c_r  = (const float*)d_in[5];
  const float* W_i  = (const float*)d_in[6];
  const float* b_i  = (const float*)d_in[7];
  const float* W_fl = (const float*)d_in[8];
  const float* b_fl = (const float*)d_in[9];
  const float* W_fr = (const float*)d_in[10];
  const float* b_fr = (const float*)d_in[11];
  const float* W_xin= (const float*)d_in[12];
  const float* W_o  = (const float*)d_in[13];
  const float* b_o  = (const float*)d_in[14];
  const float* W_z  = (const float*)d_in[15];
  const float* b_z  = (const float*)d_in[16];
  const float* W_g  = (const float*)d_in[17];
  const float* b_g  = (const float*)d_in[18];

  float* out_x = (float*)d_out;
  float* out_h = out_x + (size_t)NROWS * 1024;
  float* out_c = out_x + 2 * (size_t)NROWS * 1024;

  char* ws = (char*)d_ws;
  unsigned short* xin  = (unsigned short*)ws;                    // N x 4096
  unsigned short* A1   = (unsigned short*)ws;                    // N x 2048 (overlap)
  unsigned short* A3   = (unsigned short*)(ws + 67108864);       // N x 4096
  unsigned short* A2   = A3;                                     // N x 1024 (overlap)
  unsigned short* pre4 = (unsigned short*)(ws + 134217728);      // N x 4096
  unsigned short* zpre = pre4;
  unsigned short* opre = pre4;
  unsigned short* Wb   = (unsigned short*)(ws + 201326592);      // up to 4096x4096

  const dim3 blk(256);
  const dim3 gblk(512);
  const size_t NE = (size_t)NROWS * 1024;

  // ---- stage A: z gate -> x_t ----
  cast_bf16_kernel<<<dim3((1024u * 2048u / 4) / 256), blk, 0, stream>>>(Wb, W_z, 1024 * 2048 / 4);
  pack_cat_kernel<<<dim3((unsigned)(NE * 2 / 4 / 256)), blk, 0, stream>>>(A1, x_l, x_r, x_l, x_l, 11);
  gemm256<<<dim3((1024 / 256) * (NROWS / 256)), gblk, 0, stream>>>(A1, Wb, zpre, 2048, 2048, 2048, 1024, 1024 / 256);
  ew1_kernel<<<dim3((unsigned)(NE / 256)), blk, 0, stream>>>(zpre, b_z, x_l, x_r, out_x, A2);

  // ---- stage B: x_in = x_t @ W_xin^T ----
  cast_bf16_kernel<<<dim3((4096u * 1024u / 4) / 256), blk, 0, stream>>>(Wb, W_xin, 4096 * 1024 / 4);
  gemm256<<<dim3((4096 / 256) * (NROWS / 256)), gblk, 0, stream>>>(A2, Wb, xin, 1024, 1024, 1024, 4096, 4096 / 256);

  // ---- stage C: fused i/fl/fr/g GEMM -> c_t ----
  pack_w4_kernel<<<dim3((4096u * 4096u / 4) / 256), blk, 0, stream>>>(Wb, W_i, W_fl, W_fr, W_g);
  pack_cat_kernel<<<dim3((unsigned)(NE * 4 / 4 / 256)), blk, 0, stream>>>(A3, h_l, h_r, c_l, c_r, 12);
  gemm256<<<dim3((4096 / 256) * (NROWS / 256)), gblk, 0, stream>>>(A3, Wb, pre4, 4096, 4096, 4096, 4096, 4096 / 256);
  ew2_kernel<<<dim3((unsigned)(NE / 256)), blk, 0, stream>>>(pre4, xin, b_i, b_fl, b_fr, b_g,
                                                             c_l, c_r, out_c, A3);

  // ---- stage D: o gate -> h_t ----
  cast_bf16_kernel<<<dim3((1024u * 3072u / 4) / 256), blk, 0, stream>>>(Wb, W_o, 1024 * 3072 / 4);
  gemm256<<<dim3((1024 / 256) * (NROWS / 256)), gblk, 0, stream>>>(A3, Wb, opre, 3072, 4096, 3072, 1024, 1024 / 256);
  ew3_kernel<<<dim3((unsigned)(NE / 256)), blk, 0, stream>>>(opre, b_o, xin, out_c, out_h);
}